// Round 1
// baseline (180.907 us; speedup 1.0000x reference)
//
#include <hip/hip_runtime.h>

#define BATCH 4096
#define CTX 10
#define NEG 20
#define DIM 128
#define NWORDS (CTX + CTX * NEG)   // 210

__device__ __forceinline__ float log_sigmoid(float x) {
    // log(sigmoid(x)) = min(x,0) - log1p(exp(-|x|))   (stable)
    return fminf(x, 0.0f) - log1pf(__expf(-fabsf(x)));
}

__global__ __launch_bounds__(256) void sgns_partial(
    const float* __restrict__ emb_i, const float* __restrict__ emb_o,
    const int* __restrict__ iword, const int* __restrict__ owords,
    const int* __restrict__ nwords, float* __restrict__ partial)
{
    __shared__ int   s_idx[NWORDS];
    __shared__ float s_wsum[4];

    const int b    = blockIdx.x;
    const int tid  = threadIdx.x;
    const int lane = tid & 63;
    const int wave = tid >> 6;

    // stage the 210 gather indices for this batch row
    if (tid < CTX)
        s_idx[tid] = owords[b * CTX + tid];
    else if (tid < NWORDS)
        s_idx[tid] = nwords[b * (CTX * NEG) + (tid - CTX)];

    // each lane keeps its 2 ivec elements in registers (coalesced 512B/wave)
    const int iw = iword[b];
    const float2 iv =
        *reinterpret_cast<const float2*>(emb_i + (size_t)iw * DIM + 2 * lane);

    __syncthreads();

    float acc = 0.0f;
    // wave w handles words w, w+4, w+8, ... (53 or 52 words per wave)
    for (int j = wave; j < NWORDS; j += 4) {
        const int w = s_idx[j];
        const float2 r =
            *reinterpret_cast<const float2*>(emb_o + (size_t)w * DIM + 2 * lane);
        float p = fmaf(iv.x, r.x, iv.y * r.y);
        // 64-lane butterfly reduce (wavefront = 64 on CDNA!)
        #pragma unroll
        for (int off = 32; off > 0; off >>= 1)
            p += __shfl_xor(p, off, 64);
        const float x = (j < CTX) ? p : -p;   // negatives: log_sigmoid(-dot)
        acc += log_sigmoid(x);
    }

    // all lanes hold identical acc after the butterfly; lane 0 of each wave posts it
    if (lane == 0) s_wsum[wave] = acc;
    __syncthreads();
    if (tid == 0)
        partial[b] = s_wsum[0] + s_wsum[1] + s_wsum[2] + s_wsum[3];
}

__global__ __launch_bounds__(256) void sgns_reduce(
    const float* __restrict__ partial, float* __restrict__ out)
{
    __shared__ float s[4];
    const int tid = threadIdx.x;

    float acc = 0.0f;
    for (int i = tid; i < BATCH; i += 256) acc += partial[i];

    #pragma unroll
    for (int off = 32; off > 0; off >>= 1)
        acc += __shfl_xor(acc, off, 64);

    if ((tid & 63) == 0) s[tid >> 6] = acc;
    __syncthreads();
    if (tid == 0)
        out[0] = -(s[0] + s[1] + s[2] + s[3]) / (float)(BATCH * CTX);
}

extern "C" void kernel_launch(void* const* d_in, const int* in_sizes, int n_in,
                              void* d_out, int out_size, void* d_ws, size_t ws_size,
                              hipStream_t stream) {
    const float* emb_i  = (const float*)d_in[0];
    const float* emb_o  = (const float*)d_in[1];
    const int*   iword  = (const int*)d_in[2];
    const int*   owords = (const int*)d_in[3];
    const int*   nwords = (const int*)d_in[4];
    float* out = (float*)d_out;
    float* partial = (float*)d_ws;   // BATCH floats = 16 KB

    sgns_partial<<<BATCH, 256, 0, stream>>>(emb_i, emb_o, iword, owords,
                                            nwords, partial);
    sgns_reduce<<<1, 256, 0, stream>>>(partial, out);
}

// Round 2
// 86.934 us; speedup vs baseline: 2.0810x; 2.0810x over previous
//
#include <hip/hip_runtime.h>

#define BATCH 4096
#define CTX 10
#define NEG 20
#define DIM 128
#define NWORDS (CTX + CTX * NEG)   // 210

__device__ __forceinline__ float log_sigmoid(float x) {
    // log(sigmoid(x)) = min(x,0) - log(1 + exp(-|x|))   (stable)
    return fminf(x, 0.0f) - __logf(1.0f + __expf(-fabsf(x)));
}

__global__ __launch_bounds__(256) void sgns_partial(
    const float* __restrict__ emb_i, const float* __restrict__ emb_o,
    const int* __restrict__ iword, const int* __restrict__ owords,
    const int* __restrict__ nwords, float* __restrict__ partial)
{
    __shared__ float s_ivec[DIM];
    __shared__ float s_wsum[4];

    const int b   = blockIdx.x;
    const int tid = threadIdx.x;

    // stage this row's ivec in LDS (32 lanes x float4 = 512B, coalesced)
    const int iw = iword[b];
    if (tid < DIM / 4) {
        *reinterpret_cast<float4*>(&s_ivec[4 * tid]) =
            *reinterpret_cast<const float4*>(emb_i + (size_t)iw * DIM + 4 * tid);
    }
    __syncthreads();

    // one lane per word: thread t owns word t's full 128-dim dot
    float ls = 0.0f;
    if (tid < NWORDS) {
        const int w = (tid < CTX) ? owords[b * CTX + tid]
                                  : nwords[b * (CTX * NEG) + (tid - CTX)];
        const float* __restrict__ rp = emb_o + (size_t)w * DIM;

        float acc = 0.0f;
        #pragma unroll
        for (int d = 0; d < DIM / 4; ++d) {
            const float4 r = *reinterpret_cast<const float4*>(rp + 4 * d);
            const float4 q = *reinterpret_cast<const float4*>(&s_ivec[4 * d]); // broadcast
            acc = fmaf(q.x, r.x, acc);
            acc = fmaf(q.y, r.y, acc);
            acc = fmaf(q.z, r.z, acc);
            acc = fmaf(q.w, r.w, acc);
        }
        const float x = (tid < CTX) ? acc : -acc;  // negatives: log_sigmoid(-dot)
        ls = log_sigmoid(x);
    }

    // block-reduce 256 values (inactive lanes contribute 0)
    #pragma unroll
    for (int off = 32; off > 0; off >>= 1)
        ls += __shfl_xor(ls, off, 64);

    if ((tid & 63) == 0) s_wsum[tid >> 6] = ls;
    __syncthreads();
    if (tid == 0)
        partial[b] = s_wsum[0] + s_wsum[1] + s_wsum[2] + s_wsum[3];
}

__global__ __launch_bounds__(256) void sgns_reduce(
    const float* __restrict__ partial, float* __restrict__ out)
{
    __shared__ float s[4];
    const int tid = threadIdx.x;

    float acc = 0.0f;
    for (int i = tid; i < BATCH; i += 256) acc += partial[i];

    #pragma unroll
    for (int off = 32; off > 0; off >>= 1)
        acc += __shfl_xor(acc, off, 64);

    if ((tid & 63) == 0) s[tid >> 6] = acc;
    __syncthreads();
    if (tid == 0)
        out[0] = -(s[0] + s[1] + s[2] + s[3]) / (float)(BATCH * CTX);
}

extern "C" void kernel_launch(void* const* d_in, const int* in_sizes, int n_in,
                              void* d_out, int out_size, void* d_ws, size_t ws_size,
                              hipStream_t stream) {
    const float* emb_i  = (const float*)d_in[0];
    const float* emb_o  = (const float*)d_in[1];
    const int*   iword  = (const int*)d_in[2];
    const int*   owords = (const int*)d_in[3];
    const int*   nwords = (const int*)d_in[4];
    float* out = (float*)d_out;
    float* partial = (float*)d_ws;   // BATCH floats = 16 KB

    sgns_partial<<<BATCH, 256, 0, stream>>>(emb_i, emb_o, iword, owords,
                                            nwords, partial);
    sgns_reduce<<<1, 256, 0, stream>>>(partial, out);
}

// Round 3
// 63.225 us; speedup vs baseline: 2.8613x; 1.3750x over previous
//
#include <hip/hip_runtime.h>

#define BATCH 4096
#define CTX 10
#define NEG 20
#define DIM 128
#define NWORDS (CTX + CTX * NEG)   // 210

__device__ __forceinline__ float log_sigmoid(float x) {
    // log(sigmoid(x)) = min(x,0) - log(1 + exp(-|x|))   (stable)
    return fminf(x, 0.0f) - __logf(1.0f + __expf(-fabsf(x)));
}

__global__ __launch_bounds__(256) void sgns_partial(
    const float* __restrict__ emb_i, const float* __restrict__ emb_o,
    const int* __restrict__ iword, const int* __restrict__ owords,
    const int* __restrict__ nwords, float* __restrict__ partial)
{
    __shared__ int   s_idx[NWORDS];
    __shared__ float s_ivec[DIM];
    __shared__ float s_wsum[4];

    const int b   = blockIdx.x;
    const int tid = threadIdx.x;

    // stage ivec (32 lanes x float4) and the 210 gather indices
    const int iw = iword[b];
    if (tid < DIM / 4) {
        *reinterpret_cast<float4*>(&s_ivec[4 * tid]) =
            *reinterpret_cast<const float4*>(emb_i + (size_t)iw * DIM + 4 * tid);
    }
    if (tid < CTX)
        s_idx[tid] = owords[b * CTX + tid];
    else if (tid < NWORDS)
        s_idx[tid] = nwords[b * (CTX * NEG) + (tid - CTX)];
    __syncthreads();

    // 4 lanes per word: group grp = tid>>2 owns words grp, grp+64, grp+128, grp+192
    const int grp = tid >> 2;
    const int sub = tid & 3;
    const float4* __restrict__ q4 = reinterpret_cast<const float4*>(s_ivec) + sub;

    float acc = 0.0f;
    #pragma unroll
    for (int pass = 0; pass < 4; ++pass) {
        const int  j   = grp + 64 * pass;
        const bool act = (j < NWORDS);
        float p = 0.0f;
        if (act) {
            const float4* __restrict__ rp =
                reinterpret_cast<const float4*>(emb_o + (size_t)s_idx[j] * DIM) + sub;
            // 8 independent loads in flight (64B stride within the row)
            float4 r[8];
            #pragma unroll
            for (int u = 0; u < 8; ++u) r[u] = rp[4 * u];
            float a0 = 0.f, a1 = 0.f, a2 = 0.f, a3 = 0.f;
            #pragma unroll
            for (int u = 0; u < 8; ++u) {
                const float4 q = q4[4 * u];   // LDS broadcast (4 addrs/wave, conflict-free)
                a0 = fmaf(q.x, r[u].x, a0);
                a1 = fmaf(q.y, r[u].y, a1);
                a2 = fmaf(q.z, r[u].z, a2);
                a3 = fmaf(q.w, r[u].w, a3);
            }
            p = (a0 + a1) + (a2 + a3);
        }
        // 4-lane group reduce
        p += __shfl_xor(p, 1, 64);
        p += __shfl_xor(p, 2, 64);
        if (act) {
            const float x = (j < CTX) ? p : -p;  // negatives: log_sigmoid(-dot)
            acc += log_sigmoid(x);               // all 4 lanes add it; scale 1/4 later
        }
    }

    // block reduce (each word counted 4x -> scale 0.25)
    #pragma unroll
    for (int off = 32; off > 0; off >>= 1)
        acc += __shfl_xor(acc, off, 64);

    if ((tid & 63) == 0) s_wsum[tid >> 6] = acc;
    __syncthreads();
    if (tid == 0)
        partial[b] = 0.25f * (s_wsum[0] + s_wsum[1] + s_wsum[2] + s_wsum[3]);
}

__global__ __launch_bounds__(256) void sgns_reduce(
    const float* __restrict__ partial, float* __restrict__ out)
{
    __shared__ float s[4];
    const int tid = threadIdx.x;

    float acc = 0.0f;
    for (int i = tid; i < BATCH; i += 256) acc += partial[i];

    #pragma unroll
    for (int off = 32; off > 0; off >>= 1)
        acc += __shfl_xor(acc, off, 64);

    if ((tid & 63) == 0) s[tid >> 6] = acc;
    __syncthreads();
    if (tid == 0)
        out[0] = -(s[0] + s[1] + s[2] + s[3]) / (float)(BATCH * CTX);
}

extern "C" void kernel_launch(void* const* d_in, const int* in_sizes, int n_in,
                              void* d_out, int out_size, void* d_ws, size_t ws_size,
                              hipStream_t stream) {
    const float* emb_i  = (const float*)d_in[0];
    const float* emb_o  = (const float*)d_in[1];
    const int*   iword  = (const int*)d_in[2];
    const int*   owords = (const int*)d_in[3];
    const int*   nwords = (const int*)d_in[4];
    float* out = (float*)d_out;
    float* partial = (float*)d_ws;   // BATCH floats = 16 KB

    sgns_partial<<<BATCH, 256, 0, stream>>>(emb_i, emb_o, iword, owords,
                                            nwords, partial);
    sgns_reduce<<<1, 256, 0, stream>>>(partial, out);
}

// Round 4
// 59.000 us; speedup vs baseline: 3.0662x; 1.0716x over previous
//
#include <hip/hip_runtime.h>

#define BATCH 4096
#define CTX 10
#define NEG 20
#define DIM 128
#define NWORDS (CTX + CTX * NEG)   // 210

__device__ __forceinline__ float log_sigmoid(float x) {
    // log(sigmoid(x)) = min(x,0) - log(1 + exp(-|x|))   (stable)
    return fminf(x, 0.0f) - __logf(1.0f + __expf(-fabsf(x)));
}

__global__ __launch_bounds__(256, 4) void sgns_partial(
    const float* __restrict__ emb_i, const float* __restrict__ emb_o,
    const int* __restrict__ iword, const int* __restrict__ owords,
    const int* __restrict__ nwords, float* __restrict__ partial)
{
    __shared__ int   s_idx[NWORDS];
    __shared__ float s_ivec[DIM];
    __shared__ float s_wsum[4];

    const int b   = blockIdx.x;
    const int tid = threadIdx.x;

    // stage ivec (32 lanes x float4) and the 210 gather indices
    const int iw = iword[b];
    if (tid < DIM / 4) {
        *reinterpret_cast<float4*>(&s_ivec[4 * tid]) =
            *reinterpret_cast<const float4*>(emb_i + (size_t)iw * DIM + 4 * tid);
    }
    if (tid < CTX)
        s_idx[tid] = owords[b * CTX + tid];
    else if (tid < NWORDS)
        s_idx[tid] = nwords[b * (CTX * NEG) + (tid - CTX)];
    __syncthreads();

    // 4 lanes per word; group grp owns words grp, grp+64, grp+128, grp+192
    const int grp = tid >> 2;
    const int sub = tid & 3;

    // hoist this lane's ivec fragment to registers (reused all 4 passes)
    float4 q[8];
    #pragma unroll
    for (int u = 0; u < 8; ++u)
        q[u] = reinterpret_cast<const float4*>(s_ivec)[sub + 4 * u];

    // prologue: load pass-0 row chunk (8 independent float4, 64B stride)
    float4 cur[8], nxt[8];
    {
        const float4* __restrict__ rp =
            reinterpret_cast<const float4*>(emb_o + (size_t)s_idx[grp] * DIM) + sub;
        #pragma unroll
        for (int u = 0; u < 8; ++u) cur[u] = rp[4 * u];
    }

    float acc = 0.0f;
    #pragma unroll
    for (int p = 0; p < 4; ++p) {
        // issue next pass's loads BEFORE consuming current (always-on pipeline;
        // tail index clamped so the loads are unconditional and in-bounds)
        if (p < 3) {
            int jn = grp + 64 * (p + 1);
            jn = (jn < NWORDS) ? jn : (NWORDS - 1);
            const float4* __restrict__ rn =
                reinterpret_cast<const float4*>(emb_o + (size_t)s_idx[jn] * DIM) + sub;
            #pragma unroll
            for (int u = 0; u < 8; ++u) nxt[u] = rn[4 * u];
        }

        float a0 = 0.f, a1 = 0.f, a2 = 0.f, a3 = 0.f;
        #pragma unroll
        for (int u = 0; u < 8; ++u) {
            a0 = fmaf(q[u].x, cur[u].x, a0);
            a1 = fmaf(q[u].y, cur[u].y, a1);
            a2 = fmaf(q[u].z, cur[u].z, a2);
            a3 = fmaf(q[u].w, cur[u].w, a3);
        }
        float pd = (a0 + a1) + (a2 + a3);
        // 4-lane group reduce
        pd += __shfl_xor(pd, 1, 64);
        pd += __shfl_xor(pd, 2, 64);

        const int j = grp + 64 * p;
        if (j < NWORDS) {
            const float x = (j < CTX) ? pd : -pd;  // negatives: log_sigmoid(-dot)
            acc += log_sigmoid(x);                 // counted 4x; scale 0.25 later
        }

        if (p < 3) {
            #pragma unroll
            for (int u = 0; u < 8; ++u) cur[u] = nxt[u];  // renamed away by unroll
        }
    }

    // block reduce (each word counted 4x -> scale 0.25)
    #pragma unroll
    for (int off = 32; off > 0; off >>= 1)
        acc += __shfl_xor(acc, off, 64);

    if ((tid & 63) == 0) s_wsum[tid >> 6] = acc;
    __syncthreads();
    if (tid == 0)
        partial[b] = 0.25f * (s_wsum[0] + s_wsum[1] + s_wsum[2] + s_wsum[3]);
}

__global__ __launch_bounds__(256) void sgns_reduce(
    const float* __restrict__ partial, float* __restrict__ out)
{
    __shared__ float s[4];
    const int tid = threadIdx.x;

    // 4096 floats = 256 threads x 4 float4, coalesced
    float acc = 0.0f;
    #pragma unroll
    for (int k = 0; k < 4; ++k) {
        const float4 v = reinterpret_cast<const float4*>(partial)[tid + 256 * k];
        acc += (v.x + v.y) + (v.z + v.w);
    }

    #pragma unroll
    for (int off = 32; off > 0; off >>= 1)
        acc += __shfl_xor(acc, off, 64);

    if ((tid & 63) == 0) s[tid >> 6] = acc;
    __syncthreads();
    if (tid == 0)
        out[0] = -(s[0] + s[1] + s[2] + s[3]) / (float)(BATCH * CTX);
}

extern "C" void kernel_launch(void* const* d_in, const int* in_sizes, int n_in,
                              void* d_out, int out_size, void* d_ws, size_t ws_size,
                              hipStream_t stream) {
    const float* emb_i  = (const float*)d_in[0];
    const float* emb_o  = (const float*)d_in[1];
    const int*   iword  = (const int*)d_in[2];
    const int*   owords = (const int*)d_in[3];
    const int*   nwords = (const int*)d_in[4];
    float* out = (float*)d_out;
    float* partial = (float*)d_ws;   // BATCH floats = 16 KB

    sgns_partial<<<BATCH, 256, 0, stream>>>(emb_i, emb_o, iword, owords,
                                            nwords, partial);
    sgns_reduce<<<1, 256, 0, stream>>>(partial, out);
}